// Round 3
// baseline (217.611 us; speedup 1.0000x reference)
//
#include <hip/hip_runtime.h>

// Problem constants (B=64, C=512, H=W=32 -> HW=1024)
#define B_  64
#define C_  512
#define HW_ 1024
#define NCHUNK 16
#define CPC (C_ / NCHUNK)   // 32 channels per chunk

__device__ __forceinline__ float waveReduceSum(float v) {
    #pragma unroll
    for (int off = 32; off > 0; off >>= 1) v += __shfl_xor(v, off);
    return v;
}

__device__ __forceinline__ float waveReduceMax(float v) {
    #pragma unroll
    for (int off = 32; off > 0; off >>= 1) v = fmaxf(v, __shfl_xor(v, off));
    return v;
}

// ---------------------------------------------------------------------------
// Kernel A: partial channel dot-products (streaming read of l, 128 MiB).
// grid = B*NCHUNK = 1024 blocks, 256 threads. Block (b, chunk) computes, for
// all 1024 hw positions, sum over its 32 channels of l[b,c,hw]*w[c].
// Thread t owns one float4 of hw. Fully coalesced (1 KB per wave-load).
// ---------------------------------------------------------------------------
__global__ __launch_bounds__(256) void kA_partial_dot(
        const float* __restrict__ l,
        const float* __restrict__ w,
        float* __restrict__ part) {
    const int blk   = blockIdx.x;
    const int b     = blk / NCHUNK;
    const int chunk = blk % NCHUNK;
    const int tid   = threadIdx.x;

    const float4* l4 = reinterpret_cast<const float4*>(
        l + ((size_t)b * C_ + (size_t)chunk * CPC) * HW_);

    float4 acc = {0.f, 0.f, 0.f, 0.f};
    #pragma unroll 8
    for (int i = 0; i < CPC; ++i) {
        const float wv = w[chunk * CPC + i];        // block-uniform -> scalar
        const float4 v = l4[(size_t)i * (HW_ / 4) + tid];
        acc.x = fmaf(v.x, wv, acc.x);
        acc.y = fmaf(v.y, wv, acc.y);
        acc.z = fmaf(v.z, wv, acc.z);
        acc.w = fmaf(v.w, wv, acc.w);
    }
    reinterpret_cast<float4*>(part)[(size_t)blk * (HW_ / 4) + tid] = acc;
}

// ---------------------------------------------------------------------------
// Kernel B: fused {partial-reduce + gw + softmax + attention pooling}.
// grid = B*NCHUNK = 1024 blocks, 256 threads = 4 waves.
// Block (b, chunk): redundantly computes the FULL softmax a[b,:] for its
// batch (16 float4 partial loads/thread + block max/sum reductions), keeps
// a in LDS, then pools its own 32 channels (l re-read; L3-resident after kA).
// chunk==0 blocks also write the c logits output.
// ---------------------------------------------------------------------------
__global__ __launch_bounds__(256) void kB_softmax_pool(
        const float* __restrict__ l,
        const float* __restrict__ part,
        const float* __restrict__ g,
        const float* __restrict__ w,
        float* __restrict__ c_out,
        float* __restrict__ gout) {
    __shared__ float a_lds[HW_];
    __shared__ float red[4];

    const int blk   = blockIdx.x;
    const int b     = blk >> 4;      // / NCHUNK
    const int chunk = blk & 15;      // % NCHUNK
    const int tid   = threadIdx.x;
    const int lane  = tid & 63;
    const int wid   = tid >> 6;      // 4 waves

    // --- gw[b] = sum_c g[b,c]*w[c] (each thread covers 2 channels) ---
    float p = g[b * C_ + tid] * w[tid] + g[b * C_ + 256 + tid] * w[256 + tid];
    p = waveReduceSum(p);
    if (lane == 0) red[wid] = p;
    __syncthreads();
    const float gw = red[0] + red[1] + red[2] + red[3];

    // --- c for this thread's 4 hw positions: sum 16 chunk partials + gw ---
    const float4* part4 = reinterpret_cast<const float4*>(part);
    float4 c4 = {gw, gw, gw, gw};
    #pragma unroll
    for (int k = 0; k < NCHUNK; ++k) {
        const float4 v = part4[(size_t)(b * NCHUNK + k) * (HW_ / 4) + tid];
        c4.x += v.x; c4.y += v.y; c4.z += v.z; c4.w += v.w;
    }

    // --- block max over 1024 values ---
    float m = fmaxf(fmaxf(c4.x, c4.y), fmaxf(c4.z, c4.w));
    m = waveReduceMax(m);
    __syncthreads();                 // red[] reuse guard
    if (lane == 0) red[wid] = m;
    __syncthreads();
    m = fmaxf(fmaxf(red[0], red[1]), fmaxf(red[2], red[3]));

    // --- exp + block sum ---
    float4 e4;
    e4.x = __expf(c4.x - m);
    e4.y = __expf(c4.y - m);
    e4.z = __expf(c4.z - m);
    e4.w = __expf(c4.w - m);
    float s = e4.x + e4.y + e4.z + e4.w;
    s = waveReduceSum(s);
    __syncthreads();                 // red[] reuse guard
    if (lane == 0) red[wid] = s;
    __syncthreads();
    s = red[0] + red[1] + red[2] + red[3];
    const float inv = __frcp_rn(s);

    // --- a -> LDS; chunk 0 writes c logits output ---
    float4 a4 = {e4.x * inv, e4.y * inv, e4.z * inv, e4.w * inv};
    reinterpret_cast<float4*>(a_lds)[tid] = a4;
    if (chunk == 0)
        reinterpret_cast<float4*>(c_out + (size_t)b * HW_)[tid] = c4;
    __syncthreads();

    // --- pooling: wave `wid` handles 8 channels; a-fragment in registers ---
    float4 av[4];
    #pragma unroll
    for (int i = 0; i < 4; ++i)
        av[i] = reinterpret_cast<float4*>(a_lds)[i * 64 + lane];

    #pragma unroll
    for (int ch = 0; ch < 8; ++ch) {
        const int c = chunk * CPC + wid * 8 + ch;
        const float4* l4 = reinterpret_cast<const float4*>(
            l + ((size_t)b * C_ + c) * HW_);
        float sacc = 0.f;
        #pragma unroll
        for (int i = 0; i < 4; ++i) {
            const float4 v = l4[i * 64 + lane];
            sacc = fmaf(v.x, av[i].x, sacc);
            sacc = fmaf(v.y, av[i].y, sacc);
            sacc = fmaf(v.z, av[i].z, sacc);
            sacc = fmaf(v.w, av[i].w, sacc);
        }
        sacc = waveReduceSum(sacc);
        if (lane == 0) gout[(size_t)b * C_ + c] = sacc;
    }
}

// ---------------------------------------------------------------------------
extern "C" void kernel_launch(void* const* d_in, const int* in_sizes, int n_in,
                              void* d_out, int out_size, void* d_ws, size_t ws_size,
                              hipStream_t stream) {
    const float* l = (const float*)d_in[0];   // [B, C, H, W]
    const float* g = (const float*)d_in[1];   // [B, C]
    const float* w = (const float*)d_in[2];   // [C]
    float* out = (float*)d_out;               // c: B*HW floats, then g_out: B*C

    float* part = (float*)d_ws;               // B*NCHUNK*HW floats = 4 MiB

    kA_partial_dot<<<B_ * NCHUNK, 256, 0, stream>>>(l, w, part);
    kB_softmax_pool<<<B_ * NCHUNK, 256, 0, stream>>>(
        l, part, g, w, out, out + (size_t)B_ * HW_);
}